// Round 12
// baseline (580.238 us; speedup 1.0000x reference)
//
#include <hip/hip_runtime.h>

typedef unsigned short u16;
typedef unsigned int u32;
typedef _Float16 f16;

using half8 = __attribute__((ext_vector_type(8))) _Float16;
using f32x4 = __attribute__((ext_vector_type(4))) float;
using f32x16 = __attribute__((ext_vector_type(16))) float;

// Chunk-major activation layout (MFMA-fragment-native), per image n:
//   idx(n,k,cell) = n*32768 + (k>>4)*1024 + ((k>>3)&1)*512 + cell*8 + (k&7)
// i.e. [ks:32][khalf:2][cell:64][j:8].

// ---------------------------------------------------------------------------
// Prep 0: Qc[n] = ques[n] @ W1c + b1 (fp32). Also zero Ctx.
// ---------------------------------------------------------------------------
__global__ __launch_bounds__(512) void prep_qc(const float* __restrict__ ques,
                                               const float* __restrict__ gw1,
                                               const float* __restrict__ gb1,
                                               float* __restrict__ Qc,
                                               float* __restrict__ Ctx) {
    const int n = blockIdx.x;
    const int t = threadIdx.x;
    __shared__ float q[256];
    if (t < 256) q[t] = ques[(size_t)n * 256 + t];
    __syncthreads();
    float acc = gb1[t];
    for (int e = 0; e < 256; ++e)
        acc += q[e] * gw1[(size_t)(132 + e) * 512 + t];
    Qc[(size_t)n * 512 + t] = acc;
    Ctx[(size_t)n * 512 + t] = 0.f;
}

// ---------------------------------------------------------------------------
// Prep 1: P1c = f16(feats @ W1a + Qc[n]), P2c = f16(feats @ W1b),
// both chunk-major. (P1 fp32 round-trip eliminated.)
// ---------------------------------------------------------------------------
__global__ __launch_bounds__(512) void prep_p12(const float* __restrict__ img,
                                                const float* __restrict__ gw1,
                                                const float* __restrict__ Qc,
                                                f16* __restrict__ P1c,
                                                f16* __restrict__ P2c) {
    const int blk = blockIdx.x;
    const int n = blk >> 3;
    const int c0 = (blk & 7) * 8;
    const int t = threadIdx.x;
    __shared__ float feats[8][68];
    for (int idx = t; idx < 8 * 66; idx += 512) {
        int rr = idx / 66, cc = idx % 66, cell = c0 + rr;
        float v;
        if (cc < 64)       v = img[((size_t)(n * 64 + cc)) * 64 + cell];
        else if (cc == 64) v = (float)(cell >> 3);
        else               v = (float)(cell & 7);
        feats[rr][cc] = v;
    }
    __syncthreads();
    const int g = t;
    float a1[8], a2[8];
#pragma unroll
    for (int r = 0; r < 8; ++r) { a1[r] = 0.f; a2[r] = 0.f; }
    for (int c = 0; c < 66; ++c) {
        float wa = gw1[(size_t)c * 512 + g];
        float wb = gw1[(size_t)(66 + c) * 512 + g];
#pragma unroll
        for (int r = 0; r < 8; ++r) {
            a1[r] += feats[r][c] * wa;
            a2[r] += feats[r][c] * wb;
        }
    }
    const float qc = Qc[(size_t)n * 512 + g];
    const size_t cb = (size_t)n * 32768 + (g >> 4) * 1024 + ((g >> 3) & 1) * 512 + (g & 7);
#pragma unroll
    for (int r = 0; r < 8; ++r) {
        P1c[cb + (c0 + r) * 8] = (f16)(a1[r] + qc);
        P2c[cb + (c0 + r) * 8] = (f16)a2[r];
    }
}

// ---------------------------------------------------------------------------
// Prep 3: reorder W2/W3/W4 (512x512 fp32 [k][n]) into K-chunk-major f16:
//   T'[ks][khalf][col][8]: halfidx = ks*8192 + khalf*4096 + col*8 + (k&7)
// ---------------------------------------------------------------------------
__global__ void transpose_w(const float* __restrict__ W2, const float* __restrict__ W3,
                            const float* __restrict__ W4, f16* __restrict__ T2,
                            f16* __restrict__ T3, f16* __restrict__ T4) {
    const int L = blockIdx.z;
    const float* W = (L == 0) ? W2 : ((L == 1) ? W3 : W4);
    f16* T = (L == 0) ? T2 : ((L == 1) ? T3 : T4);
    __shared__ float tile[32][33];
    const int bx = blockIdx.x * 32;  // n origin
    const int by = blockIdx.y * 32;  // k origin
    const int tx = threadIdx.x, ty = threadIdx.y;
    for (int r = ty; r < 32; r += 8)
        tile[r][tx] = W[(size_t)(by + r) * 512 + bx + tx];
    __syncthreads();
    for (int r = ty; r < 32; r += 8) {
        const int n = bx + r, k = by + tx;
        T[(size_t)(k >> 4) * 8192 + ((k >> 3) & 1) * 4096 + n * 8 + (k & 7)] =
            (f16)tile[tx][r];
    }
}

// ---------------------------------------------------------------------------
// FUSED g-MLP layers 2..4 + mean-reduce. 32x32x16 MFMA, 1x8 N-split,
// H = 64 rows, 64 KB LDS, (512,4) -> 2 blocks/CU.
// Round-11 post-mortem: 369us, MFMA-busy 214us (floor ~170), spill is COLD
// (once/thread, 65MB = 32B/thread) -> not the lever. Remaining MFMA-idle:
// phase-aligned co-resident blocks both idle the matrix pipe in construct/
// writeback. THIS ROUND: the construct phase is DELETED -- layer-2's A
// fragment is built on the fly inside the K-loop from P1c/P2c
// (relu(x+y), 16 pk-ops/phase). y-reads are wave-identical across all 8
// waves AND both co-resident blocks (same image) -> L1-broadcast-hot
// 1KB/phase. Layer-2 does zero LDS reads; H is first written at wb(gb2)
// (its leading barrier dropped -- no prior readers). Layers 3/4 unchanged.
// Fragment layouts (guide m74/m101):
//   A/B: row|col = lane&31, k = (lane>>5)*8 + j
//   C/D: col = lane&31, row = (reg&3) + 8*(reg>>2) + 4*(lane>>5)
// ---------------------------------------------------------------------------
__global__ __launch_bounds__(512, 4) void fused_g234(
    const f16* __restrict__ P1c, const f16* __restrict__ P2c,
    const f16* __restrict__ T2, const f16* __restrict__ T3,
    const f16* __restrict__ T4, const float* __restrict__ gb2,
    const float* __restrict__ gb3, const float* __restrict__ gb4,
    float* __restrict__ Ctx) {
    const int tid = threadIdx.x;
    const int lane = tid & 63;
    const int lane31 = lane & 31;
    const int khalf = lane >> 5;        // 0..1 (k-subgroup of 8 within ks*16)
    const int wv = tid >> 6;            // 0..7 (column group of 64)
    const int b = blockIdx.x;
    const int nb = b >> 6;              // image 0..63
    const int i0 = b & 63;              // the single i-index of this block

    __shared__ alignas(16) f16 H[32 * 1024];   // 64 KB exactly -> 2 blocks/CU

    const f16* P1b = P1c + (size_t)nb * 32768;
    const f16* P2b = P2c + (size_t)nb * 32768;

    f32x16 acc[2][2];
#pragma unroll
    for (int mi = 0; mi < 2; ++mi)
#pragma unroll
        for (int ni = 0; ni < 2; ++ni)
#pragma unroll
            for (int r = 0; r < 16; ++r)
                acc[mi][ni][r] = 0.f;

    // Per-lane invariant offsets.
    //   A from LDS (layers 3/4): even ks -> f = khalf; odd ks -> f = 2|khalf.
    const int aoffE = khalf * 512 + (lane31 ^ khalf) * 8;
    const int aoffO = khalf * 512 + (lane31 ^ (2 | khalf)) * 8;
    //   A from global (layer 2): chunk-major cell offsets.
    const int ybase0 = khalf * 512 + lane31 * 8;
    const int ybase1 = khalf * 512 + (32 + lane31) * 8;
    const int xbase  = khalf * 512 + i0 * 8;
    //   B (bytes): against the SGPR-held T base; walks +16384 per ks.
    const u32 boff = (u32)(khalf * 4096 + (wv * 64 + lane31) * 8) * 2u;

    auto mfma4 = [&](half8 a0, half8 a1, half8 b0, half8 b1) {
        __builtin_amdgcn_s_setprio(1);
        acc[0][0] = __builtin_amdgcn_mfma_f32_32x32x16_f16(a0, b0, acc[0][0], 0, 0, 0);
        acc[0][1] = __builtin_amdgcn_mfma_f32_32x32x16_f16(a0, b1, acc[0][1], 0, 0, 0);
        acc[1][0] = __builtin_amdgcn_mfma_f32_32x32x16_f16(a1, b0, acc[1][0], 0, 0, 0);
        acc[1][1] = __builtin_amdgcn_mfma_f32_32x32x16_f16(a1, b1, acc[1][1], 0, 0, 0);
        __builtin_amdgcn_s_setprio(0);
    };

    // Layer 2: A built on the fly from P1c/P2c (no LDS, no construct phase).
    auto run_layer2 = [&](const f16* __restrict__ T) {
        const char* Tb = (const char*)T;
        u32 vo = boff;
        half8 bA0 = *(const half8*)(Tb + vo);
        half8 bA1 = *(const half8*)(Tb + vo + 512);
        half8 bB0, bB1;
#pragma unroll 1
        for (int k2 = 0; k2 < 16; ++k2) {
            const int cb = k2 * 2048;              // even ks chunk base (halves)
            vo += 16384;
            bB0 = *(const half8*)(Tb + vo);        // prefetch odd ks B
            bB1 = *(const half8*)(Tb + vo + 512);
            {
                half8 x  = *(const half8*)(P1b + cb + xbase);
                half8 y0 = *(const half8*)(P2b + cb + ybase0);
                half8 y1 = *(const half8*)(P2b + cb + ybase1);
                half8 a0 = __builtin_elementwise_max(x + y0, (half8)(f16)0.f);
                half8 a1 = __builtin_elementwise_max(x + y1, (half8)(f16)0.f);
                mfma4(a0, a1, bA0, bA1);
            }
            if (k2 < 15) {
                vo += 16384;
                bA0 = *(const half8*)(Tb + vo);    // prefetch next even ks B
                bA1 = *(const half8*)(Tb + vo + 512);
            }
            {
                half8 x  = *(const half8*)(P1b + cb + 1024 + xbase);
                half8 y0 = *(const half8*)(P2b + cb + 1024 + ybase0);
                half8 y1 = *(const half8*)(P2b + cb + 1024 + ybase1);
                half8 a0 = __builtin_elementwise_max(x + y0, (half8)(f16)0.f);
                half8 a1 = __builtin_elementwise_max(x + y1, (half8)(f16)0.f);
                mfma4(a0, a1, bB0, bB1);
            }
        }
    };

    // Layers 3/4: A from LDS H (chunk-major, XOR slot, 0 conflicts).
    auto run_layer = [&](const f16* __restrict__ T) {
        const char* Tb = (const char*)T;
        u32 vo = boff;
        half8 bA0 = *(const half8*)(Tb + vo);
        half8 bA1 = *(const half8*)(Tb + vo + 512);
        half8 bB0, bB1;
#pragma unroll 1
        for (int k2 = 0; k2 < 16; ++k2) {
            const int e0 = aoffE + k2 * 2048;      // even-phase A offset (halves)
            vo += 16384;
            bB0 = *(const half8*)(Tb + vo);        // prefetch odd ks
            bB1 = *(const half8*)(Tb + vo + 512);
            {
                half8 a0 = *(const half8*)&H[e0];
                half8 a1 = *(const half8*)&H[e0 + 256];
                mfma4(a0, a1, bA0, bA1);
            }
            if (k2 < 15) {
                vo += 16384;
                bA0 = *(const half8*)(Tb + vo);    // prefetch next even ks
                bA1 = *(const half8*)(Tb + vo + 512);
            }
            {
                const int o0 = aoffO + k2 * 2048 + 1024;   // odd-phase A offset
                half8 a0 = *(const half8*)&H[o0];
                half8 a1 = *(const half8*)&H[o0 + 256];
                mfma4(a0, a1, bB0, bB1);
            }
        }
    };

    // relu(acc+bias) -> f16 -> H chunk-major (slot XOR), zero acc.
    // lead_barrier=false for the first writeback (no prior H readers).
    auto writeback = [&](const float* __restrict__ bias, bool lead_barrier) {
        float bb[2];
#pragma unroll
        for (int ni = 0; ni < 2; ++ni)
            bb[ni] = bias[wv * 64 + ni * 32 + lane31];
        if (lead_barrier) __syncthreads();  // all waves done reading H
#pragma unroll
        for (int ni = 0; ni < 2; ++ni) {
            const int c = wv * 64 + ni * 32 + lane31;
            const int cbase = (c >> 4) * 1024 + ((c >> 3) & 1) * 512;
            const int fw = (((c >> 4) & 1) << 1) | ((c >> 3) & 1);
            const int j = c & 7;
#pragma unroll
            for (int mi = 0; mi < 2; ++mi) {
#pragma unroll
                for (int r = 0; r < 16; ++r) {
                    const int row = mi * 32 + (r & 3) + 4 * khalf + 8 * (r >> 2);
                    float v = fmaxf(acc[mi][ni][r] + bb[ni], 0.f);
                    H[cbase + (row ^ fw) * 8 + j] = (f16)v;
                    acc[mi][ni][r] = 0.f;
                }
            }
        }
        __syncthreads();                    // H rewrite complete
    };

    run_layer2(T2);
    writeback(gb2, false);
    run_layer(T3);
    writeback(gb3, true);
    run_layer(T4);

    // ---- layer-4 epilogue: relu(acc+b4), col-sum over the block's 64 rows ----
#pragma unroll
    for (int ni = 0; ni < 2; ++ni) {
        const int col = wv * 64 + ni * 32 + lane31;
        float bb = gb4[col];
        float s = 0.f;
#pragma unroll
        for (int mi = 0; mi < 2; ++mi)
#pragma unroll
            for (int r = 0; r < 16; ++r)
                s += fmaxf(acc[mi][ni][r] + bb, 0.f);
        s += __shfl_xor(s, 32, 64);         // combine the two khalf lanes
        if (khalf == 0)
            atomicAdd(&Ctx[(((size_t)nb) << 9) + col], s);
    }
}

// ---------------------------------------------------------------------------
// Fused f-MLP: z1 = relu(Ctx/4096 @ W1+b1); z2 = relu(z1 @ W2+b2);
// out = log_softmax(z2 @ W3 + b3). One block per image, 512 threads
// (thread = one column), 3 barriers, no HBM intermediates.
// ---------------------------------------------------------------------------
__global__ __launch_bounds__(512) void fmlp_all(
    const float* __restrict__ Ctx,
    const float* __restrict__ fw1, const float* __restrict__ fb1,
    const float* __restrict__ fw2, const float* __restrict__ fb2,
    const float* __restrict__ fw3, const float* __restrict__ fb3,
    float* __restrict__ out) {
    const int n = blockIdx.x;
    const int t = threadIdx.x;
    const int lane = t & 63;
    const int wvv = t >> 6;
    __shared__ float a[512];
    __shared__ float z[512];
    __shared__ float r0[8], r1[8];
    a[t] = Ctx[(size_t)n * 512 + t] * (1.0f / 4096.0f);
    __syncthreads();
    float p = fb1[t];
#pragma unroll 8
    for (int i = 0; i < 512; ++i)
        p += a[i] * fw1[(size_t)i * 512 + t];
    z[t] = fmaxf(p, 0.f);
    __syncthreads();
    p = fb2[t];
#pragma unroll 8
    for (int i = 0; i < 512; ++i)
        p += z[i] * fw2[(size_t)i * 512 + t];
    float z2 = fmaxf(p, 0.f);
    float v0 = z2 * fw3[t * 2];
    float v1 = z2 * fw3[t * 2 + 1];
#pragma unroll
    for (int d = 1; d < 64; d <<= 1) {
        v0 += __shfl_xor(v0, d, 64);
        v1 += __shfl_xor(v1, d, 64);
    }
    if (lane == 0) { r0[wvv] = v0; r1[wvv] = v1; }
    __syncthreads();
    if (t == 0) {
        float s0 = fb3[0], s1 = fb3[1];
#pragma unroll
        for (int w = 0; w < 8; ++w) { s0 += r0[w]; s1 += r1[w]; }
        float m = fmaxf(s0, s1);
        float l = logf(expf(s0 - m) + expf(s1 - m)) + m;
        out[n * 2 + 0] = s0 - l;
        out[n * 2 + 1] = s1 - l;
    }
}

// ---------------------------------------------------------------------------
extern "C" void kernel_launch(void* const* d_in, const int* in_sizes, int n_in,
                              void* d_out, int out_size, void* d_ws, size_t ws_size,
                              hipStream_t stream) {
    const float* img  = (const float*)d_in[0];
    const float* ques = (const float*)d_in[1];
    const float* gw1  = (const float*)d_in[2];
    const float* gb1  = (const float*)d_in[3];
    const float* gw2  = (const float*)d_in[4];
    const float* gb2  = (const float*)d_in[5];
    const float* gw3  = (const float*)d_in[6];
    const float* gb3  = (const float*)d_in[7];
    const float* gw4  = (const float*)d_in[8];
    const float* gb4  = (const float*)d_in[9];
    const float* fw1  = (const float*)d_in[10];
    const float* fb1  = (const float*)d_in[11];
    const float* fw2  = (const float*)d_in[12];
    const float* fb2  = (const float*)d_in[13];
    const float* fw3  = (const float*)d_in[14];
    const float* fb3  = (const float*)d_in[15];

    char* ws = (char*)d_ws;
    size_t off = 0;
    f16* P1c = (f16*)(ws + off); off += (size_t)4096 * 512 * 2;       // 4 MB chunk-major
    f16* P2c = (f16*)(ws + off); off += (size_t)4096 * 512 * 2;       // 4 MB chunk-major
    float* Qc  = (float*)(ws + off); off += (size_t)64 * 512 * 4;
    float* Ctx = (float*)(ws + off); off += (size_t)64 * 512 * 4;
    f16* T2 = (f16*)(ws + off); off += (size_t)512 * 512 * 2;
    f16* T3 = (f16*)(ws + off); off += (size_t)512 * 512 * 2;
    f16* T4 = (f16*)(ws + off); off += (size_t)512 * 512 * 2;

    prep_qc<<<64, 512, 0, stream>>>(ques, gw1, gb1, Qc, Ctx);
    prep_p12<<<512, 512, 0, stream>>>(img, gw1, Qc, P1c, P2c);
    transpose_w<<<dim3(16, 16, 3), dim3(32, 8), 0, stream>>>(gw2, gw3, gw4, T2, T3, T4);

    // one fused dispatch; 64-row blocks, 2 co-resident per CU
    fused_g234<<<4096, 512, 0, stream>>>(P1c, P2c, T2, T3, T4, gb2, gb3, gb4, Ctx);

    fmlp_all<<<64, 512, 0, stream>>>(Ctx, fw1, fb1, fw2, fb2, fw3, fb3, (float*)d_out);
}

// Round 13
// 537.635 us; speedup vs baseline: 1.0792x; 1.0792x over previous
//
#include <hip/hip_runtime.h>

typedef unsigned short u16;
typedef unsigned int u32;
typedef _Float16 f16;

using half8 = __attribute__((ext_vector_type(8))) _Float16;
using f32x4 = __attribute__((ext_vector_type(4))) float;
using f32x16 = __attribute__((ext_vector_type(16))) float;

// Chunk-major activation layout (MFMA-fragment-native), per image n:
//   idx(n,k,cell) = n*32768 + (k>>4)*1024 + ((k>>3)&1)*512 + cell*8 + (k&7)
// i.e. [ks:32][khalf:2][cell:64][j:8].

// ---------------------------------------------------------------------------
// MERGED PREP (one dispatch, block-role split):
//   blocks 0..511   : P1c = f16(feats@W1a + qc), P2c = f16(feats@W1b),
//                     chunk-major; qc computed INLINE (256 FMA/thread,
//                     8x redundant per image -- cheap, kills the Qc
//                     producer kernel + round-trip). One block per image
//                     also zeros Ctx.
//   blocks 512..1279: W2/W3/W4 (fp32 [k][n]) -> T' K-chunk-major f16:
//                     T'[ks][khalf][col][8], 16 KB per ks chunk ->
//                     per-wave B loads in the GEMM are contiguous 512 B.
// ---------------------------------------------------------------------------
__global__ __launch_bounds__(512) void prep_all(
    const float* __restrict__ img, const float* __restrict__ ques,
    const float* __restrict__ gw1, const float* __restrict__ gb1,
    const float* __restrict__ gw2, const float* __restrict__ gw3,
    const float* __restrict__ gw4,
    f16* __restrict__ P1c, f16* __restrict__ P2c,
    f16* __restrict__ T2, f16* __restrict__ T3, f16* __restrict__ T4,
    float* __restrict__ Ctx) {
    const int blk = blockIdx.x;
    const int t = threadIdx.x;
    __shared__ float feats[8][68];
    __shared__ float q[256];
    __shared__ float tile[32][33];

    if (blk < 512) {
        // ---- role p12 ----
        const int n = blk >> 3;
        const int c0 = (blk & 7) * 8;
        if (t < 256) q[t] = ques[(size_t)n * 256 + t];
        for (int idx = t; idx < 8 * 66; idx += 512) {
            int rr = idx / 66, cc = idx % 66, cell = c0 + rr;
            float v;
            if (cc < 64)       v = img[((size_t)(n * 64 + cc)) * 64 + cell];
            else if (cc == 64) v = (float)(cell >> 3);
            else               v = (float)(cell & 7);
            feats[rr][cc] = v;
        }
        __syncthreads();
        const int g = t;
        float qc = gb1[g];
        for (int e = 0; e < 256; ++e)
            qc += q[e] * gw1[(size_t)(132 + e) * 512 + g];
        float a1[8], a2[8];
#pragma unroll
        for (int r = 0; r < 8; ++r) { a1[r] = 0.f; a2[r] = 0.f; }
        for (int c = 0; c < 66; ++c) {
            float wa = gw1[(size_t)c * 512 + g];
            float wb = gw1[(size_t)(66 + c) * 512 + g];
#pragma unroll
            for (int r = 0; r < 8; ++r) {
                a1[r] += feats[r][c] * wa;
                a2[r] += feats[r][c] * wb;
            }
        }
        const size_t cb = (size_t)n * 32768 + (g >> 4) * 1024 + ((g >> 3) & 1) * 512 + (g & 7);
#pragma unroll
        for (int r = 0; r < 8; ++r) {
            P1c[cb + (c0 + r) * 8] = (f16)(a1[r] + qc);
            P2c[cb + (c0 + r) * 8] = (f16)a2[r];
        }
        if ((blk & 7) == 0) Ctx[(size_t)n * 512 + t] = 0.f;
    } else {
        // ---- role transpose ----
        const int tb = blk - 512;
        const int L = tb >> 8;            // 0..2
        const int rem = tb & 255;
        const int bx = (rem & 15) * 32;   // n origin
        const int by = (rem >> 4) * 32;   // k origin
        const float* W = (L == 0) ? gw2 : ((L == 1) ? gw3 : gw4);
        f16* T = (L == 0) ? T2 : ((L == 1) ? T3 : T4);
        const int tx = t & 31, ty = t >> 5;       // 32 x 16
        for (int r = ty; r < 32; r += 16)
            tile[r][tx] = W[(size_t)(by + r) * 512 + bx + tx];
        __syncthreads();
        for (int r = ty; r < 32; r += 16) {
            const int n = bx + r, k = by + tx;
            T[(size_t)(k >> 4) * 8192 + ((k >> 3) & 1) * 4096 + n * 8 + (k & 7)] =
                (f16)tile[tx][r];
        }
    }
}

// ---------------------------------------------------------------------------
// FUSED g-MLP layers 2..4 + mean-reduce (r11-proven version, verbatim).
// 32x32x16 MFMA, 1x8 N-split, H = 64 rows, 64 KB LDS, (512,4) -> 2 blk/CU.
// Round-12 post-mortem: on-the-fly layer-2 construct regressed 369->434us
// (A moved from LDS to 3 un-prefetched global loads on every phase's
// critical path; 200+cyc bubble/phase that 4 waves/SIMD can't hide).
// REVERTED to: construct once into LDS (amortized over 3 layers), K-loop
// A from LDS chunk-major (0 conflicts), B depth-1 named prefetch, lean
// addressing (arch ~50 regs <= 64 cap, only cold spill).
// Fragment layouts (guide m74/m101):
//   A/B: row|col = lane&31, k = (lane>>5)*8 + j
//   C/D: col = lane&31, row = (reg&3) + 8*(reg>>2) + 4*(lane>>5)
// ---------------------------------------------------------------------------
__global__ __launch_bounds__(512, 4) void fused_g234(
    const f16* __restrict__ P1c, const f16* __restrict__ P2c,
    const f16* __restrict__ T2, const f16* __restrict__ T3,
    const f16* __restrict__ T4, const float* __restrict__ gb2,
    const float* __restrict__ gb3, const float* __restrict__ gb4,
    float* __restrict__ Ctx) {
    const int tid = threadIdx.x;
    const int lane = tid & 63;
    const int lane31 = lane & 31;
    const int khalf = lane >> 5;        // 0..1 (k-subgroup of 8 within ks*16)
    const int wv = tid >> 6;            // 0..7 (column group of 64)
    const int b = blockIdx.x;
    const int nb = b >> 6;              // image 0..63
    const int i0 = b & 63;              // the single i-index of this block

    __shared__ alignas(16) f16 H[32 * 1024];   // 64 KB exactly -> 2 blocks/CU

    const f16* P1b = P1c + (size_t)nb * 32768;
    const f16* P2b = P2c + (size_t)nb * 32768;

    // ---- construct: H[r][k] = relu(P1[i0][k] + P2[r][k]), chunk-major ----
    // wave wv owns ks = wv*4+u. Per iter: coalesced 512B reads, 1KB LDS write.
#pragma unroll
    for (int u = 0; u < 4; ++u) {
        const int ks = wv * 4 + u;
        const int cb = ks * 1024 + khalf * 512;
        const int f = ((ks & 1) << 1) | khalf;
        half8 x = *(const half8*)(P1b + cb + i0 * 8);
#pragma unroll
        for (int rr = 0; rr < 2; ++rr) {
            half8 y = *(const half8*)(P2b + cb + (rr * 32 + lane31) * 8);
            half8 s = x + y;
            s = __builtin_elementwise_max(s, (half8)(f16)0.f);
            *(half8*)&H[cb + (rr * 32 + (lane31 ^ f)) * 8] = s;
        }
    }
    __syncthreads();

    f32x16 acc[2][2];
#pragma unroll
    for (int mi = 0; mi < 2; ++mi)
#pragma unroll
        for (int ni = 0; ni < 2; ++ni)
#pragma unroll
            for (int r = 0; r < 16; ++r)
                acc[mi][ni][r] = 0.f;

    // Per-lane invariant offsets.
    //   A (halves): even ks -> f = khalf; odd ks -> f = 2|khalf.
    const int aoffE = khalf * 512 + (lane31 ^ khalf) * 8;
    const int aoffO = khalf * 512 + (lane31 ^ (2 | khalf)) * 8;
    //   B (bytes): against the SGPR-held T base; walks +16384 per ks.
    const u32 boff = (u32)(khalf * 4096 + (wv * 64 + lane31) * 8) * 2u;

    auto mfma4 = [&](half8 a0, half8 a1, half8 b0, half8 b1) {
        __builtin_amdgcn_s_setprio(1);
        acc[0][0] = __builtin_amdgcn_mfma_f32_32x32x16_f16(a0, b0, acc[0][0], 0, 0, 0);
        acc[0][1] = __builtin_amdgcn_mfma_f32_32x32x16_f16(a0, b1, acc[0][1], 0, 0, 0);
        acc[1][0] = __builtin_amdgcn_mfma_f32_32x32x16_f16(a1, b0, acc[1][0], 0, 0, 0);
        acc[1][1] = __builtin_amdgcn_mfma_f32_32x32x16_f16(a1, b1, acc[1][1], 0, 0, 0);
        __builtin_amdgcn_s_setprio(0);
    };

    // One 512-K layer: 32 ks chunks as 16 even/odd pairs. Named B-sets
    // alternate (no copy); A read in-iteration from LDS (imm-offset pair).
    auto run_layer = [&](const f16* __restrict__ T) {
        const char* Tb = (const char*)T;
        u32 vo = boff;
        half8 bA0 = *(const half8*)(Tb + vo);
        half8 bA1 = *(const half8*)(Tb + vo + 512);
        half8 bB0, bB1;
#pragma unroll 1
        for (int k2 = 0; k2 < 16; ++k2) {
            const int e0 = aoffE + k2 * 2048;      // even-phase A offset (halves)
            vo += 16384;
            bB0 = *(const half8*)(Tb + vo);        // prefetch odd ks
            bB1 = *(const half8*)(Tb + vo + 512);
            {
                half8 a0 = *(const half8*)&H[e0];
                half8 a1 = *(const half8*)&H[e0 + 256];
                mfma4(a0, a1, bA0, bA1);
            }
            if (k2 < 15) {
                vo += 16384;
                bA0 = *(const half8*)(Tb + vo);    // prefetch next even ks
                bA1 = *(const half8*)(Tb + vo + 512);
            }
            {
                const int o0 = aoffO + k2 * 2048 + 1024;   // odd-phase A offset
                half8 a0 = *(const half8*)&H[o0];
                half8 a1 = *(const half8*)&H[o0 + 256];
                mfma4(a0, a1, bB0, bB1);
            }
        }
    };

    // relu(acc+bias) -> f16 -> H chunk-major (slot XOR). Two barriers.
    auto writeback = [&](const float* __restrict__ bias) {
        float bb[2];
#pragma unroll
        for (int ni = 0; ni < 2; ++ni)
            bb[ni] = bias[wv * 64 + ni * 32 + lane31];
        __syncthreads();                    // all waves done reading H
#pragma unroll
        for (int ni = 0; ni < 2; ++ni) {
            const int c = wv * 64 + ni * 32 + lane31;
            const int cbase = (c >> 4) * 1024 + ((c >> 3) & 1) * 512;
            const int fw = (((c >> 4) & 1) << 1) | ((c >> 3) & 1);
            const int j = c & 7;
#pragma unroll
            for (int mi = 0; mi < 2; ++mi) {
#pragma unroll
                for (int r = 0; r < 16; ++r) {
                    const int row = mi * 32 + (r & 3) + 4 * khalf + 8 * (r >> 2);
                    float v = fmaxf(acc[mi][ni][r] + bb[ni], 0.f);
                    H[cbase + (row ^ fw) * 8 + j] = (f16)v;
                    acc[mi][ni][r] = 0.f;
                }
            }
        }
        __syncthreads();                    // H rewrite complete
    };

    run_layer(T2);
    writeback(gb2);
    run_layer(T3);
    writeback(gb3);
    run_layer(T4);

    // ---- layer-4 epilogue: relu(acc+b4), col-sum over the block's 64 rows ----
#pragma unroll
    for (int ni = 0; ni < 2; ++ni) {
        const int col = wv * 64 + ni * 32 + lane31;
        float bb = gb4[col];
        float s = 0.f;
#pragma unroll
        for (int mi = 0; mi < 2; ++mi)
#pragma unroll
            for (int r = 0; r < 16; ++r)
                s += fmaxf(acc[mi][ni][r] + bb, 0.f);
        s += __shfl_xor(s, 32, 64);         // combine the two khalf lanes
        if (khalf == 0)
            atomicAdd(&Ctx[(((size_t)nb) << 9) + col], s);
    }
}

// ---------------------------------------------------------------------------
// Fused f-MLP: z1 = relu(Ctx/4096 @ W1+b1); z2 = relu(z1 @ W2+b2);
// out = log_softmax(z2 @ W3 + b3). One block per image, 512 threads.
// ---------------------------------------------------------------------------
__global__ __launch_bounds__(512) void fmlp_all(
    const float* __restrict__ Ctx,
    const float* __restrict__ fw1, const float* __restrict__ fb1,
    const float* __restrict__ fw2, const float* __restrict__ fb2,
    const float* __restrict__ fw3, const float* __restrict__ fb3,
    float* __restrict__ out) {
    const int n = blockIdx.x;
    const int t = threadIdx.x;
    const int lane = t & 63;
    const int wvv = t >> 6;
    __shared__ float a[512];
    __shared__ float z[512];
    __shared__ float r0[8], r1[8];
    a[t] = Ctx[(size_t)n * 512 + t] * (1.0f / 4096.0f);
    __syncthreads();
    float p = fb1[t];
#pragma unroll 8
    for (int i = 0; i < 512; ++i)
        p += a[i] * fw1[(size_t)i * 512 + t];
    z[t] = fmaxf(p, 0.f);
    __syncthreads();
    p = fb2[t];
#pragma unroll 8
    for (int i = 0; i < 512; ++i)
        p += z[i] * fw2[(size_t)i * 512 + t];
    float z2 = fmaxf(p, 0.f);
    float v0 = z2 * fw3[t * 2];
    float v1 = z2 * fw3[t * 2 + 1];
#pragma unroll
    for (int d = 1; d < 64; d <<= 1) {
        v0 += __shfl_xor(v0, d, 64);
        v1 += __shfl_xor(v1, d, 64);
    }
    if (lane == 0) { r0[wvv] = v0; r1[wvv] = v1; }
    __syncthreads();
    if (t == 0) {
        float s0 = fb3[0], s1 = fb3[1];
#pragma unroll
        for (int w = 0; w < 8; ++w) { s0 += r0[w]; s1 += r1[w]; }
        float m = fmaxf(s0, s1);
        float l = logf(expf(s0 - m) + expf(s1 - m)) + m;
        out[n * 2 + 0] = s0 - l;
        out[n * 2 + 1] = s1 - l;
    }
}

// ---------------------------------------------------------------------------
extern "C" void kernel_launch(void* const* d_in, const int* in_sizes, int n_in,
                              void* d_out, int out_size, void* d_ws, size_t ws_size,
                              hipStream_t stream) {
    const float* img  = (const float*)d_in[0];
    const float* ques = (const float*)d_in[1];
    const float* gw1  = (const float*)d_in[2];
    const float* gb1  = (const float*)d_in[3];
    const float* gw2  = (const float*)d_in[4];
    const float* gb2  = (const float*)d_in[5];
    const float* gw3  = (const float*)d_in[6];
    const float* gb3  = (const float*)d_in[7];
    const float* gw4  = (const float*)d_in[8];
    const float* gb4  = (const float*)d_in[9];
    const float* fw1  = (const float*)d_in[10];
    const float* fb1  = (const float*)d_in[11];
    const float* fw2  = (const float*)d_in[12];
    const float* fb2  = (const float*)d_in[13];
    const float* fw3  = (const float*)d_in[14];
    const float* fb3  = (const float*)d_in[15];

    char* ws = (char*)d_ws;
    size_t off = 0;
    f16* P1c = (f16*)(ws + off); off += (size_t)4096 * 512 * 2;       // 4 MB chunk-major
    f16* P2c = (f16*)(ws + off); off += (size_t)4096 * 512 * 2;       // 4 MB chunk-major
    float* Ctx = (float*)(ws + off); off += (size_t)64 * 512 * 4;
    f16* T2 = (f16*)(ws + off); off += (size_t)512 * 512 * 2;
    f16* T3 = (f16*)(ws + off); off += (size_t)512 * 512 * 2;
    f16* T4 = (f16*)(ws + off); off += (size_t)512 * 512 * 2;

    // one merged prep dispatch (p12 + inline-qc + Ctx-zero | weight reorder)
    prep_all<<<1280, 512, 0, stream>>>(img, ques, gw1, gb1, gw2, gw3, gw4,
                                       P1c, P2c, T2, T3, T4, Ctx);

    // one fused g-MLP dispatch; 64-row blocks, 2 co-resident per CU
    fused_g234<<<4096, 512, 0, stream>>>(P1c, P2c, T2, T3, T4, gb2, gb3, gb4, Ctx);

    fmlp_all<<<64, 512, 0, stream>>>(Ctx, fw1, fb1, fw2, fb2, fw3, fb3, (float*)d_out);
}

// Round 14
// 534.052 us; speedup vs baseline: 1.0865x; 1.0067x over previous
//
#include <hip/hip_runtime.h>

typedef unsigned short u16;
typedef unsigned int u32;
typedef _Float16 f16;

using half8 = __attribute__((ext_vector_type(8))) _Float16;
using f32x4 = __attribute__((ext_vector_type(4))) float;
using f32x16 = __attribute__((ext_vector_type(16))) float;

// Chunk-major activation layout (MFMA-fragment-native), per image n:
//   idx(n,k,cell) = n*32768 + (k>>4)*1024 + ((k>>3)&1)*512 + cell*8 + (k&7)
// i.e. [ks:32][khalf:2][cell:64][j:8].

// ---------------------------------------------------------------------------
// Prep 0: Qc[n] = ques[n] @ W1c + b1 (fp32). Also zero Ctx. (r12-proven)
// ---------------------------------------------------------------------------
__global__ __launch_bounds__(512) void prep_qc(const float* __restrict__ ques,
                                               const float* __restrict__ gw1,
                                               const float* __restrict__ gb1,
                                               float* __restrict__ Qc,
                                               float* __restrict__ Ctx) {
    const int n = blockIdx.x;
    const int t = threadIdx.x;
    __shared__ float q[256];
    if (t < 256) q[t] = ques[(size_t)n * 256 + t];
    __syncthreads();
    float acc = gb1[t];
    for (int e = 0; e < 256; ++e)
        acc += q[e] * gw1[(size_t)(132 + e) * 512 + t];
    Qc[(size_t)n * 512 + t] = acc;
    Ctx[(size_t)n * 512 + t] = 0.f;
}

// ---------------------------------------------------------------------------
// Prep 1: P1c = f16(feats@W1a + Qc[n]), P2c = f16(feats@W1b), chunk-major.
// Round-13 post-mortem: the direct chunk-major scatter (16B per 8-lane
// group at 1KB stride, 64 iterations) was the aux regression (93->149us
// across the r9..r13 arc). THIS VERSION stages the 8x512 results in LDS
// (padded [8][520] to kill the copy-out bank alias), then writes
// chunk-major FULLY COALESCED: thread u emits one half8 at
// (ks,khalf,cell)=(u>>4,(u>>3)&1,c0+(u&7)) -> consecutive threads write
// contiguous 128B runs (full cache lines).
// ---------------------------------------------------------------------------
__global__ __launch_bounds__(512) void prep_p12(const float* __restrict__ img,
                                                const float* __restrict__ gw1,
                                                const float* __restrict__ Qc,
                                                f16* __restrict__ P1c,
                                                f16* __restrict__ P2c) {
    const int blk = blockIdx.x;
    const int n = blk >> 3;
    const int c0 = (blk & 7) * 8;
    const int t = threadIdx.x;
    __shared__ float feats[8][68];
    __shared__ f16 s1[8][520];
    __shared__ f16 s2[8][520];
    for (int idx = t; idx < 8 * 66; idx += 512) {
        int rr = idx / 66, cc = idx % 66, cell = c0 + rr;
        float v;
        if (cc < 64)       v = img[((size_t)(n * 64 + cc)) * 64 + cell];
        else if (cc == 64) v = (float)(cell >> 3);
        else               v = (float)(cell & 7);
        feats[rr][cc] = v;
    }
    __syncthreads();
    const int g = t;
    float a1[8], a2[8];
#pragma unroll
    for (int r = 0; r < 8; ++r) { a1[r] = 0.f; a2[r] = 0.f; }
    for (int c = 0; c < 66; ++c) {
        float wa = gw1[(size_t)c * 512 + g];
        float wb = gw1[(size_t)(66 + c) * 512 + g];
#pragma unroll
        for (int r = 0; r < 8; ++r) {
            a1[r] += feats[r][c] * wa;
            a2[r] += feats[r][c] * wb;
        }
    }
    const float qc = Qc[(size_t)n * 512 + g];
#pragma unroll
    for (int r = 0; r < 8; ++r) {
        s1[r][g] = (f16)(a1[r] + qc);
        s2[r][g] = (f16)a2[r];
    }
    __syncthreads();
    // coalesced chunk-major copy-out: one half8 per thread per array.
    const int ks = t >> 4, kh = (t >> 3) & 1, ci = t & 7;
    const int kbase = ks * 16 + kh * 8;
    const size_t dst = (size_t)n * 32768 + ks * 1024 + kh * 512 + (c0 + ci) * 8;
    half8 v1 = *(const half8*)&s1[ci][kbase];
    half8 v2 = *(const half8*)&s2[ci][kbase];
    *(half8*)&P1c[dst] = v1;
    *(half8*)&P2c[dst] = v2;
}

// ---------------------------------------------------------------------------
// Prep 3: reorder W2/W3/W4 (512x512 fp32 [k][n]) into K-chunk-major f16:
//   T'[ks][khalf][col][8]: halfidx = ks*8192 + khalf*4096 + col*8 + (k&7)
// ---------------------------------------------------------------------------
__global__ void transpose_w(const float* __restrict__ W2, const float* __restrict__ W3,
                            const float* __restrict__ W4, f16* __restrict__ T2,
                            f16* __restrict__ T3, f16* __restrict__ T4) {
    const int L = blockIdx.z;
    const float* W = (L == 0) ? W2 : ((L == 1) ? W3 : W4);
    f16* T = (L == 0) ? T2 : ((L == 1) ? T3 : T4);
    __shared__ float tile[32][33];
    const int bx = blockIdx.x * 32;  // n origin
    const int by = blockIdx.y * 32;  // k origin
    const int tx = threadIdx.x, ty = threadIdx.y;
    for (int r = ty; r < 32; r += 8)
        tile[r][tx] = W[(size_t)(by + r) * 512 + bx + tx];
    __syncthreads();
    for (int r = ty; r < 32; r += 8) {
        const int n = bx + r, k = by + tx;
        T[(size_t)(k >> 4) * 8192 + ((k >> 3) & 1) * 4096 + n * 8 + (k & 7)] =
            (f16)tile[tx][r];
    }
}

// ---------------------------------------------------------------------------
// FUSED g-MLP layers 2..4 + mean-reduce (r11-proven version, verbatim --
// best measured 369us, MfmaUtil 58%, 0 bank conflicts, only cold spill).
// 32x32x16 MFMA, 1x8 N-split, H = 64 rows, 64 KB LDS, (512,4) -> 2 blk/CU.
// Fragment layouts (guide m74/m101):
//   A/B: row|col = lane&31, k = (lane>>5)*8 + j
//   C/D: col = lane&31, row = (reg&3) + 8*(reg>>2) + 4*(lane>>5)
// ---------------------------------------------------------------------------
__global__ __launch_bounds__(512, 4) void fused_g234(
    const f16* __restrict__ P1c, const f16* __restrict__ P2c,
    const f16* __restrict__ T2, const f16* __restrict__ T3,
    const f16* __restrict__ T4, const float* __restrict__ gb2,
    const float* __restrict__ gb3, const float* __restrict__ gb4,
    float* __restrict__ Ctx) {
    const int tid = threadIdx.x;
    const int lane = tid & 63;
    const int lane31 = lane & 31;
    const int khalf = lane >> 5;        // 0..1 (k-subgroup of 8 within ks*16)
    const int wv = tid >> 6;            // 0..7 (column group of 64)
    const int b = blockIdx.x;
    const int nb = b >> 6;              // image 0..63
    const int i0 = b & 63;              // the single i-index of this block

    __shared__ alignas(16) f16 H[32 * 1024];   // 64 KB exactly -> 2 blocks/CU

    const f16* P1b = P1c + (size_t)nb * 32768;
    const f16* P2b = P2c + (size_t)nb * 32768;

    // ---- construct: H[r][k] = relu(P1[i0][k] + P2[r][k]), chunk-major ----
#pragma unroll
    for (int u = 0; u < 4; ++u) {
        const int ks = wv * 4 + u;
        const int cb = ks * 1024 + khalf * 512;
        const int f = ((ks & 1) << 1) | khalf;
        half8 x = *(const half8*)(P1b + cb + i0 * 8);
#pragma unroll
        for (int rr = 0; rr < 2; ++rr) {
            half8 y = *(const half8*)(P2b + cb + (rr * 32 + lane31) * 8);
            half8 s = x + y;
            s = __builtin_elementwise_max(s, (half8)(f16)0.f);
            *(half8*)&H[cb + (rr * 32 + (lane31 ^ f)) * 8] = s;
        }
    }
    __syncthreads();

    f32x16 acc[2][2];
#pragma unroll
    for (int mi = 0; mi < 2; ++mi)
#pragma unroll
        for (int ni = 0; ni < 2; ++ni)
#pragma unroll
            for (int r = 0; r < 16; ++r)
                acc[mi][ni][r] = 0.f;

    // Per-lane invariant offsets.
    const int aoffE = khalf * 512 + (lane31 ^ khalf) * 8;
    const int aoffO = khalf * 512 + (lane31 ^ (2 | khalf)) * 8;
    const u32 boff = (u32)(khalf * 4096 + (wv * 64 + lane31) * 8) * 2u;

    auto mfma4 = [&](half8 a0, half8 a1, half8 b0, half8 b1) {
        __builtin_amdgcn_s_setprio(1);
        acc[0][0] = __builtin_amdgcn_mfma_f32_32x32x16_f16(a0, b0, acc[0][0], 0, 0, 0);
        acc[0][1] = __builtin_amdgcn_mfma_f32_32x32x16_f16(a0, b1, acc[0][1], 0, 0, 0);
        acc[1][0] = __builtin_amdgcn_mfma_f32_32x32x16_f16(a1, b0, acc[1][0], 0, 0, 0);
        acc[1][1] = __builtin_amdgcn_mfma_f32_32x32x16_f16(a1, b1, acc[1][1], 0, 0, 0);
        __builtin_amdgcn_s_setprio(0);
    };

    // One 512-K layer: 32 ks chunks as 16 even/odd pairs. Named B-sets
    // alternate (no copy); A read in-iteration from LDS (imm-offset pair).
    auto run_layer = [&](const f16* __restrict__ T) {
        const char* Tb = (const char*)T;
        u32 vo = boff;
        half8 bA0 = *(const half8*)(Tb + vo);
        half8 bA1 = *(const half8*)(Tb + vo + 512);
        half8 bB0, bB1;
#pragma unroll 1
        for (int k2 = 0; k2 < 16; ++k2) {
            const int e0 = aoffE + k2 * 2048;      // even-phase A offset (halves)
            vo += 16384;
            bB0 = *(const half8*)(Tb + vo);        // prefetch odd ks
            bB1 = *(const half8*)(Tb + vo + 512);
            {
                half8 a0 = *(const half8*)&H[e0];
                half8 a1 = *(const half8*)&H[e0 + 256];
                mfma4(a0, a1, bA0, bA1);
            }
            if (k2 < 15) {
                vo += 16384;
                bA0 = *(const half8*)(Tb + vo);    // prefetch next even ks
                bA1 = *(const half8*)(Tb + vo + 512);
            }
            {
                const int o0 = aoffO + k2 * 2048 + 1024;   // odd-phase A offset
                half8 a0 = *(const half8*)&H[o0];
                half8 a1 = *(const half8*)&H[o0 + 256];
                mfma4(a0, a1, bB0, bB1);
            }
        }
    };

    // relu(acc+bias) -> f16 -> H chunk-major (slot XOR). Two barriers.
    auto writeback = [&](const float* __restrict__ bias) {
        float bb[2];
#pragma unroll
        for (int ni = 0; ni < 2; ++ni)
            bb[ni] = bias[wv * 64 + ni * 32 + lane31];
        __syncthreads();                    // all waves done reading H
#pragma unroll
        for (int ni = 0; ni < 2; ++ni) {
            const int c = wv * 64 + ni * 32 + lane31;
            const int cbase = (c >> 4) * 1024 + ((c >> 3) & 1) * 512;
            const int fw = (((c >> 4) & 1) << 1) | ((c >> 3) & 1);
            const int j = c & 7;
#pragma unroll
            for (int mi = 0; mi < 2; ++mi) {
#pragma unroll
                for (int r = 0; r < 16; ++r) {
                    const int row = mi * 32 + (r & 3) + 4 * khalf + 8 * (r >> 2);
                    float v = fmaxf(acc[mi][ni][r] + bb[ni], 0.f);
                    H[cbase + (row ^ fw) * 8 + j] = (f16)v;
                    acc[mi][ni][r] = 0.f;
                }
            }
        }
        __syncthreads();                    // H rewrite complete
    };

    run_layer(T2);
    writeback(gb2);
    run_layer(T3);
    writeback(gb3);
    run_layer(T4);

    // ---- layer-4 epilogue: relu(acc+b4), col-sum over the block's 64 rows ----
#pragma unroll
    for (int ni = 0; ni < 2; ++ni) {
        const int col = wv * 64 + ni * 32 + lane31;
        float bb = gb4[col];
        float s = 0.f;
#pragma unroll
        for (int mi = 0; mi < 2; ++mi)
#pragma unroll
            for (int r = 0; r < 16; ++r)
                s += fmaxf(acc[mi][ni][r] + bb, 0.f);
        s += __shfl_xor(s, 32, 64);         // combine the two khalf lanes
        if (khalf == 0)
            atomicAdd(&Ctx[(((size_t)nb) << 9) + col], s);
    }
}

// ---------------------------------------------------------------------------
// Fused f-MLP: z1 = relu(Ctx/4096 @ W1+b1); z2 = relu(z1 @ W2+b2);
// out = log_softmax(z2 @ W3 + b3). One block per image, 512 threads.
// (r12/r13-proven.)
// ---------------------------------------------------------------------------
__global__ __launch_bounds__(512) void fmlp_all(
    const float* __restrict__ Ctx,
    const float* __restrict__ fw1, const float* __restrict__ fb1,
    const float* __restrict__ fw2, const float* __restrict__ fb2,
    const float* __restrict__ fw3, const float* __restrict__ fb3,
    float* __restrict__ out) {
    const int n = blockIdx.x;
    const int t = threadIdx.x;
    const int lane = t & 63;
    const int wvv = t >> 6;
    __shared__ float a[512];
    __shared__ float z[512];
    __shared__ float r0[8], r1[8];
    a[t] = Ctx[(size_t)n * 512 + t] * (1.0f / 4096.0f);
    __syncthreads();
    float p = fb1[t];
#pragma unroll 8
    for (int i = 0; i < 512; ++i)
        p += a[i] * fw1[(size_t)i * 512 + t];
    z[t] = fmaxf(p, 0.f);
    __syncthreads();
    p = fb2[t];
#pragma unroll 8
    for (int i = 0; i < 512; ++i)
        p += z[i] * fw2[(size_t)i * 512 + t];
    float z2 = fmaxf(p, 0.f);
    float v0 = z2 * fw3[t * 2];
    float v1 = z2 * fw3[t * 2 + 1];
#pragma unroll
    for (int d = 1; d < 64; d <<= 1) {
        v0 += __shfl_xor(v0, d, 64);
        v1 += __shfl_xor(v1, d, 64);
    }
    if (lane == 0) { r0[wvv] = v0; r1[wvv] = v1; }
    __syncthreads();
    if (t == 0) {
        float s0 = fb3[0], s1 = fb3[1];
#pragma unroll
        for (int w = 0; w < 8; ++w) { s0 += r0[w]; s1 += r1[w]; }
        float m = fmaxf(s0, s1);
        float l = logf(expf(s0 - m) + expf(s1 - m)) + m;
        out[n * 2 + 0] = s0 - l;
        out[n * 2 + 1] = s1 - l;
    }
}

// ---------------------------------------------------------------------------
extern "C" void kernel_launch(void* const* d_in, const int* in_sizes, int n_in,
                              void* d_out, int out_size, void* d_ws, size_t ws_size,
                              hipStream_t stream) {
    const float* img  = (const float*)d_in[0];
    const float* ques = (const float*)d_in[1];
    const float* gw1  = (const float*)d_in[2];
    const float* gb1  = (const float*)d_in[3];
    const float* gw2  = (const float*)d_in[4];
    const float* gb2  = (const float*)d_in[5];
    const float* gw3  = (const float*)d_in[6];
    const float* gb3  = (const float*)d_in[7];
    const float* gw4  = (const float*)d_in[8];
    const float* gb4  = (const float*)d_in[9];
    const float* fw1  = (const float*)d_in[10];
    const float* fb1  = (const float*)d_in[11];
    const float* fw2  = (const float*)d_in[12];
    const float* fb2  = (const float*)d_in[13];
    const float* fw3  = (const float*)d_in[14];
    const float* fb3  = (const float*)d_in[15];

    char* ws = (char*)d_ws;
    size_t off = 0;
    f16* P1c = (f16*)(ws + off); off += (size_t)4096 * 512 * 2;       // 4 MB chunk-major
    f16* P2c = (f16*)(ws + off); off += (size_t)4096 * 512 * 2;       // 4 MB chunk-major
    float* Qc  = (float*)(ws + off); off += (size_t)64 * 512 * 4;
    float* Ctx = (float*)(ws + off); off += (size_t)64 * 512 * 4;
    f16* T2 = (f16*)(ws + off); off += (size_t)512 * 512 * 2;
    f16* T3 = (f16*)(ws + off); off += (size_t)512 * 512 * 2;
    f16* T4 = (f16*)(ws + off); off += (size_t)512 * 512 * 2;

    prep_qc<<<64, 512, 0, stream>>>(ques, gw1, gb1, Qc, Ctx);
    prep_p12<<<512, 512, 0, stream>>>(img, gw1, Qc, P1c, P2c);
    transpose_w<<<dim3(16, 16, 3), dim3(32, 8), 0, stream>>>(gw2, gw3, gw4, T2, T3, T4);

    // one fused g-MLP dispatch; 64-row blocks, 2 co-resident per CU
    fused_g234<<<4096, 512, 0, stream>>>(P1c, P2c, T2, T3, T4, gb2, gb3, gb4, Ctx);

    fmlp_all<<<64, 512, 0, stream>>>(Ctx, fw1, fb1, fw2, fb2, fw3, fb3, (float*)d_out);
}